// Round 7
// baseline (153.638 us; speedup 1.0000x reference)
//
#include <hip/hip_runtime.h>

// PositionalCharacterLevelWordSparse:
//   rows = B*W = 65536, L = 16 chars/row, D = 512 + 16 = 528 bins/row.
//   out[row, tok[row,c]]       += (tok != 0)
//   out[row, 512 + pos[row,c]] += (tok != 0)
//
// R7: persistent-block pipeline. 2048 blocks x 4 row-groups each
// (256 thr, 8 rows/group, 16.9 KB LDS -> 8 blocks/CU = 32 waves/CU).
// Per group: zero -> bar -> scatter + prefetch next inputs -> bar ->
// ds_read + nontemporal store (fire-and-forget: no vmcnt wait, no 3rd
// barrier -- each wave re-zeroes exactly the slice it just ds_read, a
// within-wave ordering the compiler's lgkmcnt already enforces; cross-wave
// scatter hazards are covered by the zero->scatter barrier).
// Goal: overlap each group's store drain with the next group's prologue,
// and pay input-load latency once per block, not once per 33 KB stored.

constexpr int NUM_EMB = 512;
constexpr int MAX_POS = 16;
constexpr int D = NUM_EMB + MAX_POS;     // 528
constexpr int L = 16;
constexpr int RPG = 8;                   // rows per group
constexpr int THREADS = 256;
constexpr int SCATTER = RPG * L;         // 128
constexpr int HIST = RPG * D;            // 4224 floats = 16.9 KB
constexpr int HIST4 = HIST / 4;          // 1056
constexpr int FULL_IT = HIST4 / THREADS; // 4
constexpr int REM = HIST4 - FULL_IT * THREADS;  // 32
constexpr int NBLOCKS = 2048;            // 8 blocks/CU on 256 CUs
constexpr int TOTAL_ROWS = 65536;
constexpr int GROUPS = TOTAL_ROWS / RPG;         // 8192
constexpr int GPB = GROUPS / NBLOCKS;            // 4 groups per block

typedef float v4f __attribute__((ext_vector_type(4)));

__global__ __launch_bounds__(THREADS)
void pcls_hist_kernel(const int* __restrict__ tok,
                      const int* __restrict__ pos,
                      float* __restrict__ out) {
    __shared__ float hist[HIST];

    const int tid = threadIdx.x;
    int g = blockIdx.x;                  // current group; strides by NBLOCKS

    // Prefetch group 0's inputs (latency overlaps first zero phase).
    int t = 0, p = 0;
    if (tid < SCATTER) {
        const long long base = (long long)g * (RPG * L) + tid;
        t = tok[base];
        p = pos[base];
    }

    v4f* h4 = reinterpret_cast<v4f*>(hist);

    #pragma unroll
    for (int it = 0; it < GPB; ++it) {
        // Zero this group's histograms (each wave zeroes its own slice).
        #pragma unroll
        for (int i = 0; i < FULL_IT; ++i)
            h4[tid + i * THREADS] = (v4f)0.0f;
        if (tid < REM)
            h4[tid + FULL_IT * THREADS] = (v4f)0.0f;
        __syncthreads();

        // Scatter current group (mask BOTH adds on padding).
        if (tid < SCATTER && t != 0) {
            const int r = tid >> 4;      // tid / L
            atomicAdd(&hist[r * D + t], 1.0f);          // ds_add_f32
            atomicAdd(&hist[r * D + NUM_EMB + p], 1.0f);
        }

        // Prefetch NEXT group's inputs; latency hides under barrier+store.
        int tn = 0, pn = 0;
        if (it + 1 < GPB && tid < SCATTER) {
            const long long base = (long long)(g + NBLOCKS) * (RPG * L) + tid;
            tn = tok[base];
            pn = pos[base];
        }
        __syncthreads();

        // Read + stream out (nontemporal, fire-and-forget).
        v4f* out4 = reinterpret_cast<v4f*>(out + (long long)g * (RPG * D));
        #pragma unroll
        for (int i = 0; i < FULL_IT; ++i)
            __builtin_nontemporal_store(h4[tid + i * THREADS],
                                        &out4[tid + i * THREADS]);
        if (tid < REM)
            __builtin_nontemporal_store(h4[tid + FULL_IT * THREADS],
                                        &out4[tid + FULL_IT * THREADS]);

        t = tn; p = pn; g += NBLOCKS;
    }
}

extern "C" void kernel_launch(void* const* d_in, const int* in_sizes, int n_in,
                              void* d_out, int out_size, void* d_ws, size_t ws_size,
                              hipStream_t stream) {
    const int* tok = (const int*)d_in[0];
    const int* pos = (const int*)d_in[1];
    float* out = (float*)d_out;

    pcls_hist_kernel<<<NBLOCKS, THREADS, 0, stream>>>(tok, pos, out);
}